// Round 16
// baseline (359.471 us; speedup 1.0000x reference)
//
#include <hip/hip_runtime.h>
#include <hip/hip_bf16.h>

#define N_NODES 100000
#define N_EDGES 1600000
#define DIM 128
#define N_LAYERS 3

// two-level binned CSR build, LDS-staged, deterministic (no global atomics)
#define NBUCK 256
#define BUCK_NODES 391  // ceil(N/256); bucket CSR segment ~25KB
#define CHUNK 7168      // edges per pass-A block (7 x 256 x 4)
#define ABLOCKS ((N_EDGES + CHUNK - 1) / CHUNK)  // 224
#define BCAP 8192       // pass-B LDS capacity (mean bucket = 6250, 24 sigma)

typedef __attribute__((ext_vector_type(8))) short bf16x8;
typedef __attribute__((ext_vector_type(4))) float f32x4;
typedef __attribute__((ext_vector_type(4))) uint u32x4;

__device__ __forceinline__ ushort f2bf(float f) {
  union { float f; uint u; } v;
  v.f = f;
  uint r = v.u + 0x7fffu + ((v.u >> 16) & 1u);  // RNE
  return (ushort)(r >> 16);
}
__device__ __forceinline__ float u2f(uint u) {
  union { uint u; float f; } v;
  v.u = u;
  return v.f;
}

// ---------------------------------------------------------------------------
// Wt[l][n][k] (bf16) = W[l][k][n]  — 3 x 128 x 128
// ---------------------------------------------------------------------------
__global__ __launch_bounds__(256) void prep_wt(const float* __restrict__ W,
                                               ushort* __restrict__ Wt) {
  const int i = blockIdx.x * 256 + threadIdx.x;  // < 3*128*128
  const int l = i >> 14, rem = i & 16383;
  const int k = rem >> 7, n = rem & 127;
  Wt[(size_t)l * 16384 + n * DIM + k] = f2bf(W[(size_t)l * 16384 + k * DIM + n]);
}

// ---------------------------------------------------------------------------
// MFMA GEMM with SWAPPED operands: (X@W)^T fragment layout -> row-contiguous
// 8B stores per lane.
// ---------------------------------------------------------------------------
__global__ __launch_bounds__(256) void gemm_f32in(const float* __restrict__ X,
                                                  const ushort* __restrict__ Wt,
                                                  ushort* __restrict__ H) {
  const int wid = threadIdx.x >> 6, lane = threadIdx.x & 63;
  const int row0 = blockIdx.x * 64 + wid * 16;
  if (row0 >= N_NODES) return;
  const int r = lane & 15, kg = lane >> 4;
  const size_t row = row0 + r;

  bf16x8 a[4];
#pragma unroll
  for (int c = 0; c < 4; ++c) {
    const float4 u = *(const float4*)&X[row * DIM + c * 32 + kg * 8];
    const float4 v = *(const float4*)&X[row * DIM + c * 32 + kg * 8 + 4];
    a[c][0] = (short)f2bf(u.x); a[c][1] = (short)f2bf(u.y);
    a[c][2] = (short)f2bf(u.z); a[c][3] = (short)f2bf(u.w);
    a[c][4] = (short)f2bf(v.x); a[c][5] = (short)f2bf(v.y);
    a[c][6] = (short)f2bf(v.z); a[c][7] = (short)f2bf(v.w);
  }
#pragma unroll
  for (int t = 0; t < 8; ++t) {
    f32x4 acc = {0.f, 0.f, 0.f, 0.f};
#pragma unroll
    for (int c = 0; c < 4; ++c) {
      const bf16x8 bw = *(const bf16x8*)&Wt[(size_t)(t * 16 + r) * DIM + c * 32 + kg * 8];
      acc = __builtin_amdgcn_mfma_f32_16x16x32_bf16(bw, a[c], acc, 0, 0, 0);
    }
    uint2 p;
    p.x = (uint)f2bf(acc[0]) | ((uint)f2bf(acc[1]) << 16);
    p.y = (uint)f2bf(acc[2]) | ((uint)f2bf(acc[3]) << 16);
    *(uint2*)&H[(size_t)(row0 + r) * DIM + t * 16 + kg * 4] = p;
  }
}

__global__ __launch_bounds__(256) void gemm_bf16in(const ushort* __restrict__ X,
                                                   const ushort* __restrict__ Wt,
                                                   ushort* __restrict__ H) {
  const int wid = threadIdx.x >> 6, lane = threadIdx.x & 63;
  const int row0 = blockIdx.x * 64 + wid * 16;
  if (row0 >= N_NODES) return;
  const int r = lane & 15, kg = lane >> 4;
  const size_t row = row0 + r;

  bf16x8 a[4];
#pragma unroll
  for (int c = 0; c < 4; ++c)
    a[c] = *(const bf16x8*)&X[row * DIM + c * 32 + kg * 8];
#pragma unroll
  for (int t = 0; t < 8; ++t) {
    f32x4 acc = {0.f, 0.f, 0.f, 0.f};
#pragma unroll
    for (int c = 0; c < 4; ++c) {
      const bf16x8 bw = *(const bf16x8*)&Wt[(size_t)(t * 16 + r) * DIM + c * 32 + kg * 8];
      acc = __builtin_amdgcn_mfma_f32_16x16x32_bf16(bw, a[c], acc, 0, 0, 0);
    }
    uint2 p;
    p.x = (uint)f2bf(acc[0]) | ((uint)f2bf(acc[1]) << 16);
    p.y = (uint)f2bf(acc[2]) | ((uint)f2bf(acc[3]) << 16);
    *(uint2*)&H[(size_t)(row0 + r) * DIM + t * 16 + kg * 4] = p;
  }
}

// ---------------------------------------------------------------------------
// CSR build, deterministic 3-kernel pipeline + LDS bucket build
// ---------------------------------------------------------------------------

// Pass A1: per-chunk LDS bucket histogram -> cnt2d[chunk][bucket] (coalesced)
__global__ __launch_bounds__(256) void bin_hist(const int* __restrict__ dst,
                                                int* __restrict__ cnt2d) {
  __shared__ int hist[NBUCK];
  const int tid = threadIdx.x;
  const int base = blockIdx.x * CHUNK;
  hist[tid] = 0;
  __syncthreads();
#pragma unroll
  for (int it = 0; it < CHUNK / 1024; ++it) {
    const int e0 = base + (it * 256 + tid) * 4;
    if (e0 >= N_EDGES) continue;
    const int4 d4 = *(const int4*)&dst[e0];
    atomicAdd(&hist[d4.x / BUCK_NODES], 1);
    atomicAdd(&hist[d4.y / BUCK_NODES], 1);
    atomicAdd(&hist[d4.z / BUCK_NODES], 1);
    atomicAdd(&hist[d4.w / BUCK_NODES], 1);
  }
  __syncthreads();
  cnt2d[blockIdx.x * NBUCK + tid] = hist[tid];
}

// Pass A2 (1 block): per-bucket prefix over chunks + bucket-base scan.
__global__ __launch_bounds__(256) void bin_scan(int* __restrict__ cnt2d,
                                                int* __restrict__ bbase,
                                                int* __restrict__ row_ptr) {
  __shared__ int sh[NBUCK];
  const int t = threadIdx.x;
  int sum = 0;
#pragma unroll 4
  for (int i = 0; i < ABLOCKS; ++i) {
    const int v = cnt2d[i * NBUCK + t];
    cnt2d[i * NBUCK + t] = sum;
    sum += v;
  }
  sh[t] = sum;
  __syncthreads();
  for (int off = 1; off < NBUCK; off <<= 1) {
    const int a = (t >= off) ? sh[t - off] : 0;
    __syncthreads();
    sh[t] += a;
    __syncthreads();
  }
  const int bb = sh[t] - sum;  // exclusive bucket base
  bbase[t] = bb;
  if (t == NBUCK - 1) bbase[NBUCK] = sh[t];
  if (t == 0) row_ptr[N_NODES] = N_EDGES;
#pragma unroll 4
  for (int i = 0; i < ABLOCKS; ++i) cnt2d[i * NBUCK + t] += bb;
}

// Pass A3: block-local LDS bucket sort of a chunk, contiguous run dumps at
// precomputed deterministic bases (no global atomics at all).
__global__ __launch_bounds__(256) void bin_scatter(
    const int* __restrict__ src, const int* __restrict__ dst,
    const float* __restrict__ ew, const int* __restrict__ cnt2d,
    uint2* __restrict__ ebuf) {
  __shared__ uint2 stage[CHUNK];  // 56 KB
  __shared__ int hist[NBUCK];
  __shared__ int offs[NBUCK];
  __shared__ int bstart[NBUCK];
  __shared__ int gbase[NBUCK];
  const int base = blockIdx.x * CHUNK;
  const int tid = threadIdx.x;

  hist[tid] = 0;
  gbase[tid] = cnt2d[blockIdx.x * NBUCK + tid];
  __syncthreads();

#pragma unroll
  for (int it = 0; it < CHUNK / 1024; ++it) {
    const int e0 = base + (it * 256 + tid) * 4;
    if (e0 >= N_EDGES) continue;
    const int4 d4 = *(const int4*)&dst[e0];
    atomicAdd(&hist[d4.x / BUCK_NODES], 1);
    atomicAdd(&hist[d4.y / BUCK_NODES], 1);
    atomicAdd(&hist[d4.z / BUCK_NODES], 1);
    atomicAdd(&hist[d4.w / BUCK_NODES], 1);
  }
  __syncthreads();

  const int v = hist[tid];
  bstart[tid] = v;
  __syncthreads();
  for (int off = 1; off < NBUCK; off <<= 1) {
    const int a = (tid >= off) ? bstart[tid - off] : 0;
    __syncthreads();
    bstart[tid] += a;
    __syncthreads();
  }
  const int ex = bstart[tid] - v;
  __syncthreads();
  bstart[tid] = ex;
  offs[tid] = ex;
  __syncthreads();

#pragma unroll
  for (int it = 0; it < CHUNK / 1024; ++it) {
    const int e0 = base + (it * 256 + tid) * 4;
    if (e0 >= N_EDGES) continue;
    const int4 d4 = *(const int4*)&dst[e0];
    const int4 s4 = *(const int4*)&src[e0];
    const float4 w4 = *(const float4*)&ew[e0];
#pragma unroll
    for (int j = 0; j < 4; ++j) {
      const int d = (j == 0) ? d4.x : (j == 1) ? d4.y : (j == 2) ? d4.z : d4.w;
      const int s = (j == 0) ? s4.x : (j == 1) ? s4.y : (j == 2) ? s4.z : s4.w;
      const float w = (j == 0) ? w4.x : (j == 1) ? w4.y : (j == 2) ? w4.z
                                                                   : w4.w;
      uint wfix = (uint)(w * 32768.0f + 0.5f);
      wfix = (wfix > 32767u) ? 32767u : wfix;
      const int pos = atomicAdd(&offs[d / BUCK_NODES], 1);
      uint2 p;
      p.x = (uint)d;
      p.y = (uint)s | (wfix << 17);
      stage[pos] = p;
    }
  }
  __syncthreads();

  int total = N_EDGES - base;
  if (total > CHUNK) total = CHUNK;
  for (int i = tid; i < total; i += 256) {
    const uint2 e = stage[i];
    const int b = (int)e.x / BUCK_NODES;
    ebuf[gbase[b] + (i - bstart[b])] = e;
  }
}

// Pass B: one block per bucket; derive node counts + row_ptr in LDS, build
// the bucket's CSR segment in LDS, dump sequentially.
__global__ __launch_bounds__(512) void bucket_build(
    const int* __restrict__ bbase, const uint2* __restrict__ ebuf,
    uint* __restrict__ ecsr, int* __restrict__ row_ptr) {
  __shared__ uint outb[BCAP];  // 32 KB
  __shared__ int sh[512];
  __shared__ int cur[BUCK_NODES];
  const int b = blockIdx.x;
  const int n0 = b * BUCK_NODES;
  if (n0 >= N_NODES) return;
  int n1 = n0 + BUCK_NODES;
  if (n1 > N_NODES) n1 = N_NODES;
  const int nn = n1 - n0;
  const int beg = bbase[b];
  const int end = bbase[b + 1];
  const int t = threadIdx.x;

  if (t < BUCK_NODES) cur[t] = 0;
  __syncthreads();
  for (int i = beg + t; i < end; i += 512)
    atomicAdd(&cur[(int)ebuf[i].x - n0], 1);
  __syncthreads();
  const int v = (t < nn) ? cur[t] : 0;
  sh[t] = v;
  __syncthreads();
  for (int off = 1; off < 512; off <<= 1) {
    const int a = (t >= off) ? sh[t - off] : 0;
    __syncthreads();
    sh[t] += a;
    __syncthreads();
  }
  const int ex = sh[t] - v;
  if (t < nn) {
    row_ptr[n0 + t] = beg + ex;
    cur[t] = ex;
  }
  __syncthreads();
  for (int i = beg + t; i < end; i += 512) {
    const uint2 e = ebuf[i];
    const int local = atomicAdd(&cur[(int)e.x - n0], 1);
    outb[local] = e.y;
  }
  __syncthreads();
  const int cnt = end - beg;
  for (int i = t; i < cnt; i += 512) ecsr[beg + i] = outb[i];
}

// ---------------------------------------------------------------------------
// aggregate: out[n][:] = relu( sum_{e} H[col[e]][:]*wv[e] + bias )
// one QUARTER-wave (16 lanes) per node, 8 bf16 cols per lane (16B loads),
// 16-edge unroll (32B of descriptors -> 16 row-gathers in flight per
// quarter-wave), 4-edge + scalar tails.
// ---------------------------------------------------------------------------
template <int OUTF32>
__global__ __launch_bounds__(256) void aggregate_b(
    const ushort* __restrict__ H, const int* __restrict__ row_ptr,
    const uint* __restrict__ ecsr, const float* __restrict__ bias,
    float* __restrict__ outf, ushort* __restrict__ outb) {
  const int node = blockIdx.x * 16 + (threadIdx.x >> 4);
  const int lane = threadIdx.x & 15;  // 16 lanes, 8 cols each
  if (node >= N_NODES) return;
  int i = row_ptr[node];
  const int end = row_ptr[node + 1];
  float a0 = 0.f, a1 = 0.f, a2 = 0.f, a3 = 0.f;
  float a4 = 0.f, a5 = 0.f, a6 = 0.f, a7 = 0.f;
  const float wscale = 1.0f / 32768.0f;
  for (; i + 16 <= end; i += 16) {
    uint e[16];
    u32x4 h[16];
#pragma unroll
    for (int j = 0; j < 16; ++j) e[j] = ecsr[i + j];
#pragma unroll
    for (int j = 0; j < 16; ++j)
      h[j] = *(const u32x4*)&H[(size_t)(e[j] & 0x1FFFFu) * DIM + lane * 8];
#pragma unroll
    for (int j = 0; j < 16; ++j) {
      const float w = (float)(e[j] >> 17) * wscale;
      a0 += w * u2f(h[j].x << 16);
      a1 += w * u2f(h[j].x & 0xffff0000u);
      a2 += w * u2f(h[j].y << 16);
      a3 += w * u2f(h[j].y & 0xffff0000u);
      a4 += w * u2f(h[j].z << 16);
      a5 += w * u2f(h[j].z & 0xffff0000u);
      a6 += w * u2f(h[j].w << 16);
      a7 += w * u2f(h[j].w & 0xffff0000u);
    }
  }
  for (; i + 4 <= end; i += 4) {
    uint e[4];
    u32x4 h[4];
#pragma unroll
    for (int j = 0; j < 4; ++j) e[j] = ecsr[i + j];
#pragma unroll
    for (int j = 0; j < 4; ++j)
      h[j] = *(const u32x4*)&H[(size_t)(e[j] & 0x1FFFFu) * DIM + lane * 8];
#pragma unroll
    for (int j = 0; j < 4; ++j) {
      const float w = (float)(e[j] >> 17) * wscale;
      a0 += w * u2f(h[j].x << 16);
      a1 += w * u2f(h[j].x & 0xffff0000u);
      a2 += w * u2f(h[j].y << 16);
      a3 += w * u2f(h[j].y & 0xffff0000u);
      a4 += w * u2f(h[j].z << 16);
      a5 += w * u2f(h[j].z & 0xffff0000u);
      a6 += w * u2f(h[j].w << 16);
      a7 += w * u2f(h[j].w & 0xffff0000u);
    }
  }
  for (; i < end; ++i) {
    const uint e0 = ecsr[i];
    const float w = (float)(e0 >> 17) * wscale;
    const u32x4 h0 = *(const u32x4*)&H[(size_t)(e0 & 0x1FFFFu) * DIM + lane * 8];
    a0 += w * u2f(h0.x << 16);
    a1 += w * u2f(h0.x & 0xffff0000u);
    a2 += w * u2f(h0.y << 16);
    a3 += w * u2f(h0.y & 0xffff0000u);
    a4 += w * u2f(h0.z << 16);
    a5 += w * u2f(h0.z & 0xffff0000u);
    a6 += w * u2f(h0.w << 16);
    a7 += w * u2f(h0.w & 0xffff0000u);
  }
  const float4 b0 = *(const float4*)&bias[lane * 8];
  const float4 b1 = *(const float4*)&bias[lane * 8 + 4];
  a0 = fmaxf(a0 + b0.x, 0.f);
  a1 = fmaxf(a1 + b0.y, 0.f);
  a2 = fmaxf(a2 + b0.z, 0.f);
  a3 = fmaxf(a3 + b0.w, 0.f);
  a4 = fmaxf(a4 + b1.x, 0.f);
  a5 = fmaxf(a5 + b1.y, 0.f);
  a6 = fmaxf(a6 + b1.z, 0.f);
  a7 = fmaxf(a7 + b1.w, 0.f);
  if (OUTF32) {
    float4 o0 = {a0, a1, a2, a3};
    float4 o1 = {a4, a5, a6, a7};
    *(float4*)&outf[(size_t)node * DIM + lane * 8] = o0;
    *(float4*)&outf[(size_t)node * DIM + lane * 8 + 4] = o1;
  } else {
    u32x4 p;
    p.x = (uint)f2bf(a0) | ((uint)f2bf(a1) << 16);
    p.y = (uint)f2bf(a2) | ((uint)f2bf(a3) << 16);
    p.z = (uint)f2bf(a4) | ((uint)f2bf(a5) << 16);
    p.w = (uint)f2bf(a6) | ((uint)f2bf(a7) << 16);
    *(u32x4*)&outb[(size_t)node * DIM + lane * 8] = p;
  }
}

extern "C" void kernel_launch(void* const* d_in, const int* in_sizes, int n_in,
                              void* d_out, int out_size, void* d_ws,
                              size_t ws_size, hipStream_t stream) {
  const float* x = (const float*)d_in[0];
  const int* esrc = (const int*)d_in[1];
  const int* edst = (const int*)d_in[2];
  const float* ew = (const float*)d_in[3];
  const float* W = (const float*)d_in[4];
  const float* b = (const float*)d_in[5];
  float* out = (float*)d_out;

  // workspace layout
  ushort* h_buf = (ushort*)d_ws;                        // [N*D] bf16
  ushort* act_buf = h_buf + (size_t)N_NODES * DIM;      // [N*D] bf16
  ushort* Wt = act_buf + (size_t)N_NODES * DIM;         // [3*128*128] bf16
  uint* ecsr = (uint*)(Wt + 3 * DIM * DIM);             // [E] packed src|w
  uint2* ebuf = (uint2*)(ecsr + N_EDGES);               // [E] (dst, src|w)
  int* cnt2d = (int*)(ebuf + N_EDGES);                  // [ABLOCKS*NBUCK]
  int* bbase = cnt2d + ABLOCKS * NBUCK;                 // [NBUCK+1]
  int* row_ptr = bbase + NBUCK + 1;                     // [N+1]

  prep_wt<<<3 * DIM * DIM / 256, 256, 0, stream>>>(W, Wt);

  // ---- CSR build (once, reused by all 3 layers) ----
  bin_hist<<<ABLOCKS, 256, 0, stream>>>(edst, cnt2d);
  bin_scan<<<1, 256, 0, stream>>>(cnt2d, bbase, row_ptr);
  bin_scatter<<<ABLOCKS, 256, 0, stream>>>(esrc, edst, ew, cnt2d, ebuf);
  bucket_build<<<NBUCK, 512, 0, stream>>>(bbase, ebuf, ecsr, row_ptr);

  const int gemm_blocks = (N_NODES + 63) / 64;  // 1563
  const int agg_blocks = (N_NODES + 15) / 16;   // 6250

  // layer 0: fp32 x -> h ; aggregate -> act (bf16)
  gemm_f32in<<<gemm_blocks, 256, 0, stream>>>(x, Wt, h_buf);
  aggregate_b<0><<<agg_blocks, 256, 0, stream>>>(h_buf, row_ptr, ecsr, b,
                                                 nullptr, act_buf);
  // layer 1: act -> h ; aggregate -> act
  gemm_bf16in<<<gemm_blocks, 256, 0, stream>>>(act_buf, Wt + DIM * DIM, h_buf);
  aggregate_b<0><<<agg_blocks, 256, 0, stream>>>(h_buf, row_ptr, ecsr, b + DIM,
                                                 nullptr, act_buf);
  // layer 2: act -> h ; aggregate -> out (fp32)
  gemm_bf16in<<<gemm_blocks, 256, 0, stream>>>(act_buf, Wt + 2 * DIM * DIM,
                                               h_buf);
  aggregate_b<1><<<agg_blocks, 256, 0, stream>>>(h_buf, row_ptr, ecsr,
                                                 b + 2 * DIM, out, nullptr);
}

// Round 17
// 301.207 us; speedup vs baseline: 1.1934x; 1.1934x over previous
//
#include <hip/hip_runtime.h>
#include <hip/hip_bf16.h>

#define N_NODES 100000
#define N_EDGES 1600000
#define DIM 128
#define N_LAYERS 3

// two-level binned CSR build, LDS-staged, deterministic (no global atomics)
#define NBUCK 256
#define BUCK_NODES 391  // ceil(N/256); bucket CSR segment ~25KB
#define CHUNK 7168      // edges per pass-A block (7 x 256 x 4)
#define ABLOCKS ((N_EDGES + CHUNK - 1) / CHUNK)  // 224
#define BCAP 8192       // pass-B LDS capacity (mean bucket = 6250, 24 sigma)

#define WPAD 136  // LDS row stride (shorts) for Wt: 272B -> bank stride 4

typedef __attribute__((ext_vector_type(8))) short bf16x8;
typedef __attribute__((ext_vector_type(4))) float f32x4;
typedef __attribute__((ext_vector_type(4))) uint u32x4;

__device__ __forceinline__ ushort f2bf(float f) {
  union { float f; uint u; } v;
  v.f = f;
  uint r = v.u + 0x7fffu + ((v.u >> 16) & 1u);  // RNE
  return (ushort)(r >> 16);
}
__device__ __forceinline__ float u2f(uint u) {
  union { uint u; float f; } v;
  v.u = u;
  return v.f;
}

// ---------------------------------------------------------------------------
// Wt[l][n][k] (bf16) = W[l][k][n]  — 3 x 128 x 128
// ---------------------------------------------------------------------------
__global__ __launch_bounds__(256) void prep_wt(const float* __restrict__ W,
                                               ushort* __restrict__ Wt) {
  const int i = blockIdx.x * 256 + threadIdx.x;  // < 3*128*128
  const int l = i >> 14, rem = i & 16383;
  const int k = rem >> 7, n = rem & 127;
  Wt[(size_t)l * 16384 + n * DIM + k] = f2bf(W[(size_t)l * 16384 + k * DIM + n]);
}

// ---------------------------------------------------------------------------
// MFMA GEMM, swapped operands ((X@W)^T fragments -> row-contiguous 8B stores).
// Wt staged in LDS once per block: B-fragments via ds_read_b128 instead of
// 32 global loads/wave through a thrashing L1.
// ---------------------------------------------------------------------------
__global__ __launch_bounds__(256) void gemm_f32in(const float* __restrict__ X,
                                                  const ushort* __restrict__ Wt,
                                                  ushort* __restrict__ H) {
  __shared__ ushort Ws[128][WPAD];
  const int tid = threadIdx.x;
  for (int i = tid; i < 128 * 16; i += 256) {
    const int row = i >> 4, c8 = i & 15;
    *(bf16x8*)&Ws[row][c8 * 8] = *(const bf16x8*)&Wt[row * DIM + c8 * 8];
  }
  __syncthreads();

  const int wid = tid >> 6, lane = tid & 63;
  const int row0 = blockIdx.x * 64 + wid * 16;
  if (row0 >= N_NODES) return;
  const int r = lane & 15, kg = lane >> 4;
  const size_t row = row0 + r;

  bf16x8 a[4];
#pragma unroll
  for (int c = 0; c < 4; ++c) {
    const float4 u = *(const float4*)&X[row * DIM + c * 32 + kg * 8];
    const float4 v = *(const float4*)&X[row * DIM + c * 32 + kg * 8 + 4];
    a[c][0] = (short)f2bf(u.x); a[c][1] = (short)f2bf(u.y);
    a[c][2] = (short)f2bf(u.z); a[c][3] = (short)f2bf(u.w);
    a[c][4] = (short)f2bf(v.x); a[c][5] = (short)f2bf(v.y);
    a[c][6] = (short)f2bf(v.z); a[c][7] = (short)f2bf(v.w);
  }
#pragma unroll
  for (int t = 0; t < 8; ++t) {
    f32x4 acc = {0.f, 0.f, 0.f, 0.f};
#pragma unroll
    for (int c = 0; c < 4; ++c) {
      const bf16x8 bw = *(const bf16x8*)&Ws[t * 16 + r][c * 32 + kg * 8];
      acc = __builtin_amdgcn_mfma_f32_16x16x32_bf16(bw, a[c], acc, 0, 0, 0);
    }
    uint2 p;
    p.x = (uint)f2bf(acc[0]) | ((uint)f2bf(acc[1]) << 16);
    p.y = (uint)f2bf(acc[2]) | ((uint)f2bf(acc[3]) << 16);
    *(uint2*)&H[(size_t)(row0 + r) * DIM + t * 16 + kg * 4] = p;
  }
}

__global__ __launch_bounds__(256) void gemm_bf16in(const ushort* __restrict__ X,
                                                   const ushort* __restrict__ Wt,
                                                   ushort* __restrict__ H) {
  __shared__ ushort Ws[128][WPAD];
  const int tid = threadIdx.x;
  for (int i = tid; i < 128 * 16; i += 256) {
    const int row = i >> 4, c8 = i & 15;
    *(bf16x8*)&Ws[row][c8 * 8] = *(const bf16x8*)&Wt[row * DIM + c8 * 8];
  }
  __syncthreads();

  const int wid = tid >> 6, lane = tid & 63;
  const int row0 = blockIdx.x * 64 + wid * 16;
  if (row0 >= N_NODES) return;
  const int r = lane & 15, kg = lane >> 4;
  const size_t row = row0 + r;

  bf16x8 a[4];
#pragma unroll
  for (int c = 0; c < 4; ++c)
    a[c] = *(const bf16x8*)&X[row * DIM + c * 32 + kg * 8];
#pragma unroll
  for (int t = 0; t < 8; ++t) {
    f32x4 acc = {0.f, 0.f, 0.f, 0.f};
#pragma unroll
    for (int c = 0; c < 4; ++c) {
      const bf16x8 bw = *(const bf16x8*)&Ws[t * 16 + r][c * 32 + kg * 8];
      acc = __builtin_amdgcn_mfma_f32_16x16x32_bf16(bw, a[c], acc, 0, 0, 0);
    }
    uint2 p;
    p.x = (uint)f2bf(acc[0]) | ((uint)f2bf(acc[1]) << 16);
    p.y = (uint)f2bf(acc[2]) | ((uint)f2bf(acc[3]) << 16);
    *(uint2*)&H[(size_t)(row0 + r) * DIM + t * 16 + kg * 4] = p;
  }
}

// ---------------------------------------------------------------------------
// CSR build, deterministic 3-kernel pipeline + LDS bucket build
// ---------------------------------------------------------------------------

// Pass A1: per-chunk LDS bucket histogram -> cnt2d[chunk][bucket] (coalesced)
__global__ __launch_bounds__(256) void bin_hist(const int* __restrict__ dst,
                                                int* __restrict__ cnt2d) {
  __shared__ int hist[NBUCK];
  const int tid = threadIdx.x;
  const int base = blockIdx.x * CHUNK;
  hist[tid] = 0;
  __syncthreads();
#pragma unroll
  for (int it = 0; it < CHUNK / 1024; ++it) {
    const int e0 = base + (it * 256 + tid) * 4;
    if (e0 >= N_EDGES) continue;
    const int4 d4 = *(const int4*)&dst[e0];
    atomicAdd(&hist[d4.x / BUCK_NODES], 1);
    atomicAdd(&hist[d4.y / BUCK_NODES], 1);
    atomicAdd(&hist[d4.z / BUCK_NODES], 1);
    atomicAdd(&hist[d4.w / BUCK_NODES], 1);
  }
  __syncthreads();
  cnt2d[blockIdx.x * NBUCK + tid] = hist[tid];
}

// Pass A2 (1 block): per-bucket prefix over chunks + bucket-base scan.
__global__ __launch_bounds__(256) void bin_scan(int* __restrict__ cnt2d,
                                                int* __restrict__ bbase,
                                                int* __restrict__ row_ptr) {
  __shared__ int sh[NBUCK];
  const int t = threadIdx.x;
  int sum = 0;
  for (int i = 0; i < ABLOCKS; ++i) {
    const int v = cnt2d[i * NBUCK + t];
    cnt2d[i * NBUCK + t] = sum;
    sum += v;
  }
  sh[t] = sum;
  __syncthreads();
  for (int off = 1; off < NBUCK; off <<= 1) {
    const int a = (t >= off) ? sh[t - off] : 0;
    __syncthreads();
    sh[t] += a;
    __syncthreads();
  }
  const int bb = sh[t] - sum;  // exclusive bucket base
  bbase[t] = bb;
  if (t == NBUCK - 1) bbase[NBUCK] = sh[t];
  if (t == 0) row_ptr[N_NODES] = N_EDGES;
  for (int i = 0; i < ABLOCKS; ++i) cnt2d[i * NBUCK + t] += bb;
}

// Pass A3: block-local LDS bucket sort of a chunk, contiguous run dumps at
// precomputed deterministic bases (no global atomics at all).
__global__ __launch_bounds__(256) void bin_scatter(
    const int* __restrict__ src, const int* __restrict__ dst,
    const float* __restrict__ ew, const int* __restrict__ cnt2d,
    uint2* __restrict__ ebuf) {
  __shared__ uint2 stage[CHUNK];  // 56 KB
  __shared__ int hist[NBUCK];
  __shared__ int offs[NBUCK];
  __shared__ int bstart[NBUCK];
  __shared__ int gbase[NBUCK];
  const int base = blockIdx.x * CHUNK;
  const int tid = threadIdx.x;

  hist[tid] = 0;
  gbase[tid] = cnt2d[blockIdx.x * NBUCK + tid];
  __syncthreads();

#pragma unroll
  for (int it = 0; it < CHUNK / 1024; ++it) {
    const int e0 = base + (it * 256 + tid) * 4;
    if (e0 >= N_EDGES) continue;
    const int4 d4 = *(const int4*)&dst[e0];
    atomicAdd(&hist[d4.x / BUCK_NODES], 1);
    atomicAdd(&hist[d4.y / BUCK_NODES], 1);
    atomicAdd(&hist[d4.z / BUCK_NODES], 1);
    atomicAdd(&hist[d4.w / BUCK_NODES], 1);
  }
  __syncthreads();

  const int v = hist[tid];
  bstart[tid] = v;
  __syncthreads();
  for (int off = 1; off < NBUCK; off <<= 1) {
    const int a = (tid >= off) ? bstart[tid - off] : 0;
    __syncthreads();
    bstart[tid] += a;
    __syncthreads();
  }
  const int ex = bstart[tid] - v;
  __syncthreads();
  bstart[tid] = ex;
  offs[tid] = ex;
  __syncthreads();

#pragma unroll
  for (int it = 0; it < CHUNK / 1024; ++it) {
    const int e0 = base + (it * 256 + tid) * 4;
    if (e0 >= N_EDGES) continue;
    const int4 d4 = *(const int4*)&dst[e0];
    const int4 s4 = *(const int4*)&src[e0];
    const float4 w4 = *(const float4*)&ew[e0];
#pragma unroll
    for (int j = 0; j < 4; ++j) {
      const int d = (j == 0) ? d4.x : (j == 1) ? d4.y : (j == 2) ? d4.z : d4.w;
      const int s = (j == 0) ? s4.x : (j == 1) ? s4.y : (j == 2) ? s4.z : s4.w;
      const float w = (j == 0) ? w4.x : (j == 1) ? w4.y : (j == 2) ? w4.z
                                                                   : w4.w;
      uint wfix = (uint)(w * 32768.0f + 0.5f);
      wfix = (wfix > 32767u) ? 32767u : wfix;
      const int pos = atomicAdd(&offs[d / BUCK_NODES], 1);
      uint2 p;
      p.x = (uint)d;
      p.y = (uint)s | (wfix << 17);
      stage[pos] = p;
    }
  }
  __syncthreads();

  int total = N_EDGES - base;
  if (total > CHUNK) total = CHUNK;
  for (int i = tid; i < total; i += 256) {
    const uint2 e = stage[i];
    const int b = (int)e.x / BUCK_NODES;
    ebuf[gbase[b] + (i - bstart[b])] = e;
  }
}

// Pass B: one block per bucket; derive node counts + row_ptr in LDS, build
// the bucket's CSR segment in LDS, dump sequentially.
__global__ __launch_bounds__(512) void bucket_build(
    const int* __restrict__ bbase, const uint2* __restrict__ ebuf,
    uint* __restrict__ ecsr, int* __restrict__ row_ptr) {
  __shared__ uint outb[BCAP];  // 32 KB
  __shared__ int sh[512];
  __shared__ int cur[BUCK_NODES];
  const int b = blockIdx.x;
  const int n0 = b * BUCK_NODES;
  if (n0 >= N_NODES) return;
  int n1 = n0 + BUCK_NODES;
  if (n1 > N_NODES) n1 = N_NODES;
  const int nn = n1 - n0;
  const int beg = bbase[b];
  const int end = bbase[b + 1];
  const int t = threadIdx.x;

  if (t < BUCK_NODES) cur[t] = 0;
  __syncthreads();
  for (int i = beg + t; i < end; i += 512)
    atomicAdd(&cur[(int)ebuf[i].x - n0], 1);
  __syncthreads();
  const int v = (t < nn) ? cur[t] : 0;
  sh[t] = v;
  __syncthreads();
  for (int off = 1; off < 512; off <<= 1) {
    const int a = (t >= off) ? sh[t - off] : 0;
    __syncthreads();
    sh[t] += a;
    __syncthreads();
  }
  const int ex = sh[t] - v;
  if (t < nn) {
    row_ptr[n0 + t] = beg + ex;
    cur[t] = ex;
  }
  __syncthreads();
  for (int i = beg + t; i < end; i += 512) {
    const uint2 e = ebuf[i];
    const int local = atomicAdd(&cur[(int)e.x - n0], 1);
    outb[local] = e.y;
  }
  __syncthreads();
  const int cnt = end - beg;
  for (int i = t; i < cnt; i += 512) ecsr[beg + i] = outb[i];
}

// ---------------------------------------------------------------------------
// aggregate: out[n][:] = relu( sum_{e} H[col[e]][:]*wv[e] + bias )
// one QUARTER-wave (16 lanes) per node, 8 bf16 cols per lane (16B loads),
// 8-edge unroll (R15 best). 4B descriptors.
// ---------------------------------------------------------------------------
template <int OUTF32>
__global__ __launch_bounds__(256) void aggregate_b(
    const ushort* __restrict__ H, const int* __restrict__ row_ptr,
    const uint* __restrict__ ecsr, const float* __restrict__ bias,
    float* __restrict__ outf, ushort* __restrict__ outb) {
  const int node = blockIdx.x * 16 + (threadIdx.x >> 4);
  const int lane = threadIdx.x & 15;  // 16 lanes, 8 cols each
  if (node >= N_NODES) return;
  int i = row_ptr[node];
  const int end = row_ptr[node + 1];
  float a0 = 0.f, a1 = 0.f, a2 = 0.f, a3 = 0.f;
  float a4 = 0.f, a5 = 0.f, a6 = 0.f, a7 = 0.f;
  const float wscale = 1.0f / 32768.0f;
  for (; i + 8 <= end; i += 8) {
    uint e[8];
    u32x4 h[8];
#pragma unroll
    for (int j = 0; j < 8; ++j) e[j] = ecsr[i + j];
#pragma unroll
    for (int j = 0; j < 8; ++j)
      h[j] = *(const u32x4*)&H[(size_t)(e[j] & 0x1FFFFu) * DIM + lane * 8];
#pragma unroll
    for (int j = 0; j < 8; ++j) {
      const float w = (float)(e[j] >> 17) * wscale;
      a0 += w * u2f(h[j].x << 16);
      a1 += w * u2f(h[j].x & 0xffff0000u);
      a2 += w * u2f(h[j].y << 16);
      a3 += w * u2f(h[j].y & 0xffff0000u);
      a4 += w * u2f(h[j].z << 16);
      a5 += w * u2f(h[j].z & 0xffff0000u);
      a6 += w * u2f(h[j].w << 16);
      a7 += w * u2f(h[j].w & 0xffff0000u);
    }
  }
  for (; i < end; ++i) {
    const uint e0 = ecsr[i];
    const float w = (float)(e0 >> 17) * wscale;
    const u32x4 h0 = *(const u32x4*)&H[(size_t)(e0 & 0x1FFFFu) * DIM + lane * 8];
    a0 += w * u2f(h0.x << 16);
    a1 += w * u2f(h0.x & 0xffff0000u);
    a2 += w * u2f(h0.y << 16);
    a3 += w * u2f(h0.y & 0xffff0000u);
    a4 += w * u2f(h0.z << 16);
    a5 += w * u2f(h0.z & 0xffff0000u);
    a6 += w * u2f(h0.w << 16);
    a7 += w * u2f(h0.w & 0xffff0000u);
  }
  const float4 b0 = *(const float4*)&bias[lane * 8];
  const float4 b1 = *(const float4*)&bias[lane * 8 + 4];
  a0 = fmaxf(a0 + b0.x, 0.f);
  a1 = fmaxf(a1 + b0.y, 0.f);
  a2 = fmaxf(a2 + b0.z, 0.f);
  a3 = fmaxf(a3 + b0.w, 0.f);
  a4 = fmaxf(a4 + b1.x, 0.f);
  a5 = fmaxf(a5 + b1.y, 0.f);
  a6 = fmaxf(a6 + b1.z, 0.f);
  a7 = fmaxf(a7 + b1.w, 0.f);
  if (OUTF32) {
    float4 o0 = {a0, a1, a2, a3};
    float4 o1 = {a4, a5, a6, a7};
    *(float4*)&outf[(size_t)node * DIM + lane * 8] = o0;
    *(float4*)&outf[(size_t)node * DIM + lane * 8 + 4] = o1;
  } else {
    u32x4 p;
    p.x = (uint)f2bf(a0) | ((uint)f2bf(a1) << 16);
    p.y = (uint)f2bf(a2) | ((uint)f2bf(a3) << 16);
    p.z = (uint)f2bf(a4) | ((uint)f2bf(a5) << 16);
    p.w = (uint)f2bf(a6) | ((uint)f2bf(a7) << 16);
    *(u32x4*)&outb[(size_t)node * DIM + lane * 8] = p;
  }
}

extern "C" void kernel_launch(void* const* d_in, const int* in_sizes, int n_in,
                              void* d_out, int out_size, void* d_ws,
                              size_t ws_size, hipStream_t stream) {
  const float* x = (const float*)d_in[0];
  const int* esrc = (const int*)d_in[1];
  const int* edst = (const int*)d_in[2];
  const float* ew = (const float*)d_in[3];
  const float* W = (const float*)d_in[4];
  const float* b = (const float*)d_in[5];
  float* out = (float*)d_out;

  // workspace layout
  ushort* h_buf = (ushort*)d_ws;                        // [N*D] bf16
  ushort* act_buf = h_buf + (size_t)N_NODES * DIM;      // [N*D] bf16
  ushort* Wt = act_buf + (size_t)N_NODES * DIM;         // [3*128*128] bf16
  uint* ecsr = (uint*)(Wt + 3 * DIM * DIM);             // [E] packed src|w
  uint2* ebuf = (uint2*)(ecsr + N_EDGES);               // [E] (dst, src|w)
  int* cnt2d = (int*)(ebuf + N_EDGES);                  // [ABLOCKS*NBUCK]
  int* bbase = cnt2d + ABLOCKS * NBUCK;                 // [NBUCK+1]
  int* row_ptr = bbase + NBUCK + 1;                     // [N+1]

  prep_wt<<<3 * DIM * DIM / 256, 256, 0, stream>>>(W, Wt);

  // ---- CSR build (once, reused by all 3 layers) ----
  bin_hist<<<ABLOCKS, 256, 0, stream>>>(edst, cnt2d);
  bin_scan<<<1, 256, 0, stream>>>(cnt2d, bbase, row_ptr);
  bin_scatter<<<ABLOCKS, 256, 0, stream>>>(esrc, edst, ew, cnt2d, ebuf);
  bucket_build<<<NBUCK, 512, 0, stream>>>(bbase, ebuf, ecsr, row_ptr);

  const int gemm_blocks = (N_NODES + 63) / 64;  // 1563
  const int agg_blocks = (N_NODES + 15) / 16;   // 6250

  // layer 0: fp32 x -> h ; aggregate -> act (bf16)
  gemm_f32in<<<gemm_blocks, 256, 0, stream>>>(x, Wt, h_buf);
  aggregate_b<0><<<agg_blocks, 256, 0, stream>>>(h_buf, row_ptr, ecsr, b,
                                                 nullptr, act_buf);
  // layer 1: act -> h ; aggregate -> act
  gemm_bf16in<<<gemm_blocks, 256, 0, stream>>>(act_buf, Wt + DIM * DIM, h_buf);
  aggregate_b<0><<<agg_blocks, 256, 0, stream>>>(h_buf, row_ptr, ecsr, b + DIM,
                                                 nullptr, act_buf);
  // layer 2: act -> h ; aggregate -> out (fp32)
  gemm_bf16in<<<gemm_blocks, 256, 0, stream>>>(act_buf, Wt + 2 * DIM * DIM,
                                               h_buf);
  aggregate_b<1><<<agg_blocks, 256, 0, stream>>>(h_buf, row_ptr, ecsr,
                                                 b + 2 * DIM, out, nullptr);
}

// Round 18
// 221.443 us; speedup vs baseline: 1.6233x; 1.3602x over previous
//
#include <hip/hip_runtime.h>
#include <hip/hip_bf16.h>

#define N_NODES 100000
#define N_EDGES 1600000
#define DIM 128
#define N_LAYERS 3

// two-level binned CSR build, LDS-staged, deterministic (no global atomics)
#define NBUCK 256
#define BUCK_NODES 391  // ceil(N/256); bucket CSR segment ~25KB
#define CHUNK 7168      // edges per pass-A block (7 x 256 x 4)
#define ABLOCKS ((N_EDGES + CHUNK - 1) / CHUNK)  // 224
#define BCAP 8192       // pass-B LDS capacity (mean bucket = 6250, 24 sigma)

#define WPAD 136  // LDS row stride (shorts) for Wt

typedef __attribute__((ext_vector_type(8))) short bf16x8;
typedef __attribute__((ext_vector_type(4))) float f32x4;
typedef __attribute__((ext_vector_type(2))) float f32x2;
typedef __attribute__((ext_vector_type(4))) uint u32x4;

__device__ __forceinline__ ushort f2bf(float f) {
  union { float f; uint u; } v;
  v.f = f;
  uint r = v.u + 0x7fffu + ((v.u >> 16) & 1u);  // RNE
  return (ushort)(r >> 16);
}
__device__ __forceinline__ float u2f(uint u) {
  union { uint u; float f; } v;
  v.u = u;
  return v.f;
}

// ---------------------------------------------------------------------------
// Wt[l][n][k] (bf16) = W[l][k][n]  — 3 x 128 x 128
// ---------------------------------------------------------------------------
__global__ __launch_bounds__(256) void prep_wt(const float* __restrict__ W,
                                               ushort* __restrict__ Wt) {
  const int i = blockIdx.x * 256 + threadIdx.x;  // < 3*128*128
  const int l = i >> 14, rem = i & 16383;
  const int k = rem >> 7, n = rem & 127;
  Wt[(size_t)l * 16384 + n * DIM + k] = f2bf(W[(size_t)l * 16384 + k * DIM + n]);
}

// ---------------------------------------------------------------------------
// MFMA GEMM, swapped operands ((X@W)^T fragments -> row-contiguous stores).
// Wt staged in LDS. H output is FP8 e4m3 (1 byte/elem): row = 128B = 1 line,
// halving the aggregate gather's line traffic. Pack 4 accs -> one 4B store.
// ---------------------------------------------------------------------------
__global__ __launch_bounds__(256) void gemm_f32in(const float* __restrict__ X,
                                                  const ushort* __restrict__ Wt,
                                                  uchar* __restrict__ H8) {
  __shared__ ushort Ws[128][WPAD];
  const int tid = threadIdx.x;
  for (int i = tid; i < 128 * 16; i += 256) {
    const int row = i >> 4, c8 = i & 15;
    *(bf16x8*)&Ws[row][c8 * 8] = *(const bf16x8*)&Wt[row * DIM + c8 * 8];
  }
  __syncthreads();

  const int wid = tid >> 6, lane = tid & 63;
  const int row0 = blockIdx.x * 64 + wid * 16;
  if (row0 >= N_NODES) return;
  const int r = lane & 15, kg = lane >> 4;
  const size_t row = row0 + r;

  bf16x8 a[4];
#pragma unroll
  for (int c = 0; c < 4; ++c) {
    const float4 u = *(const float4*)&X[row * DIM + c * 32 + kg * 8];
    const float4 v = *(const float4*)&X[row * DIM + c * 32 + kg * 8 + 4];
    a[c][0] = (short)f2bf(u.x); a[c][1] = (short)f2bf(u.y);
    a[c][2] = (short)f2bf(u.z); a[c][3] = (short)f2bf(u.w);
    a[c][4] = (short)f2bf(v.x); a[c][5] = (short)f2bf(v.y);
    a[c][6] = (short)f2bf(v.z); a[c][7] = (short)f2bf(v.w);
  }
#pragma unroll
  for (int t = 0; t < 8; ++t) {
    f32x4 acc = {0.f, 0.f, 0.f, 0.f};
#pragma unroll
    for (int c = 0; c < 4; ++c) {
      const bf16x8 bw = *(const bf16x8*)&Ws[t * 16 + r][c * 32 + kg * 8];
      acc = __builtin_amdgcn_mfma_f32_16x16x32_bf16(bw, a[c], acc, 0, 0, 0);
    }
    uint p = (uint)__builtin_amdgcn_cvt_pk_fp8_f32(acc[0], acc[1], 0, false);
    p = (uint)__builtin_amdgcn_cvt_pk_fp8_f32(acc[2], acc[3], (int)p, true);
    *(uint*)&H8[(size_t)(row0 + r) * DIM + t * 16 + kg * 4] = p;
  }
}

__global__ __launch_bounds__(256) void gemm_bf16in(const ushort* __restrict__ X,
                                                   const ushort* __restrict__ Wt,
                                                   uchar* __restrict__ H8) {
  __shared__ ushort Ws[128][WPAD];
  const int tid = threadIdx.x;
  for (int i = tid; i < 128 * 16; i += 256) {
    const int row = i >> 4, c8 = i & 15;
    *(bf16x8*)&Ws[row][c8 * 8] = *(const bf16x8*)&Wt[row * DIM + c8 * 8];
  }
  __syncthreads();

  const int wid = tid >> 6, lane = tid & 63;
  const int row0 = blockIdx.x * 64 + wid * 16;
  if (row0 >= N_NODES) return;
  const int r = lane & 15, kg = lane >> 4;
  const size_t row = row0 + r;

  bf16x8 a[4];
#pragma unroll
  for (int c = 0; c < 4; ++c)
    a[c] = *(const bf16x8*)&X[row * DIM + c * 32 + kg * 8];
#pragma unroll
  for (int t = 0; t < 8; ++t) {
    f32x4 acc = {0.f, 0.f, 0.f, 0.f};
#pragma unroll
    for (int c = 0; c < 4; ++c) {
      const bf16x8 bw = *(const bf16x8*)&Ws[t * 16 + r][c * 32 + kg * 8];
      acc = __builtin_amdgcn_mfma_f32_16x16x32_bf16(bw, a[c], acc, 0, 0, 0);
    }
    uint p = (uint)__builtin_amdgcn_cvt_pk_fp8_f32(acc[0], acc[1], 0, false);
    p = (uint)__builtin_amdgcn_cvt_pk_fp8_f32(acc[2], acc[3], (int)p, true);
    *(uint*)&H8[(size_t)(row0 + r) * DIM + t * 16 + kg * 4] = p;
  }
}

// ---------------------------------------------------------------------------
// CSR build, deterministic 3-kernel pipeline + LDS bucket build
// ---------------------------------------------------------------------------

__global__ __launch_bounds__(256) void bin_hist(const int* __restrict__ dst,
                                                int* __restrict__ cnt2d) {
  __shared__ int hist[NBUCK];
  const int tid = threadIdx.x;
  const int base = blockIdx.x * CHUNK;
  hist[tid] = 0;
  __syncthreads();
#pragma unroll
  for (int it = 0; it < CHUNK / 1024; ++it) {
    const int e0 = base + (it * 256 + tid) * 4;
    if (e0 >= N_EDGES) continue;
    const int4 d4 = *(const int4*)&dst[e0];
    atomicAdd(&hist[d4.x / BUCK_NODES], 1);
    atomicAdd(&hist[d4.y / BUCK_NODES], 1);
    atomicAdd(&hist[d4.z / BUCK_NODES], 1);
    atomicAdd(&hist[d4.w / BUCK_NODES], 1);
  }
  __syncthreads();
  cnt2d[blockIdx.x * NBUCK + tid] = hist[tid];
}

__global__ __launch_bounds__(256) void bin_scan(int* __restrict__ cnt2d,
                                                int* __restrict__ bbase,
                                                int* __restrict__ row_ptr) {
  __shared__ int sh[NBUCK];
  const int t = threadIdx.x;
  int sum = 0;
  for (int i = 0; i < ABLOCKS; ++i) {
    const int v = cnt2d[i * NBUCK + t];
    cnt2d[i * NBUCK + t] = sum;
    sum += v;
  }
  sh[t] = sum;
  __syncthreads();
  for (int off = 1; off < NBUCK; off <<= 1) {
    const int a = (t >= off) ? sh[t - off] : 0;
    __syncthreads();
    sh[t] += a;
    __syncthreads();
  }
  const int bb = sh[t] - sum;  // exclusive bucket base
  bbase[t] = bb;
  if (t == NBUCK - 1) bbase[NBUCK] = sh[t];
  if (t == 0) row_ptr[N_NODES] = N_EDGES;
  for (int i = 0; i < ABLOCKS; ++i) cnt2d[i * NBUCK + t] += bb;
}

__global__ __launch_bounds__(256) void bin_scatter(
    const int* __restrict__ src, const int* __restrict__ dst,
    const float* __restrict__ ew, const int* __restrict__ cnt2d,
    uint2* __restrict__ ebuf) {
  __shared__ uint2 stage[CHUNK];  // 56 KB
  __shared__ int hist[NBUCK];
  __shared__ int offs[NBUCK];
  __shared__ int bstart[NBUCK];
  __shared__ int gbase[NBUCK];
  const int base = blockIdx.x * CHUNK;
  const int tid = threadIdx.x;

  hist[tid] = 0;
  gbase[tid] = cnt2d[blockIdx.x * NBUCK + tid];
  __syncthreads();

#pragma unroll
  for (int it = 0; it < CHUNK / 1024; ++it) {
    const int e0 = base + (it * 256 + tid) * 4;
    if (e0 >= N_EDGES) continue;
    const int4 d4 = *(const int4*)&dst[e0];
    atomicAdd(&hist[d4.x / BUCK_NODES], 1);
    atomicAdd(&hist[d4.y / BUCK_NODES], 1);
    atomicAdd(&hist[d4.z / BUCK_NODES], 1);
    atomicAdd(&hist[d4.w / BUCK_NODES], 1);
  }
  __syncthreads();

  const int v = hist[tid];
  bstart[tid] = v;
  __syncthreads();
  for (int off = 1; off < NBUCK; off <<= 1) {
    const int a = (tid >= off) ? bstart[tid - off] : 0;
    __syncthreads();
    bstart[tid] += a;
    __syncthreads();
  }
  const int ex = bstart[tid] - v;
  __syncthreads();
  bstart[tid] = ex;
  offs[tid] = ex;
  __syncthreads();

#pragma unroll
  for (int it = 0; it < CHUNK / 1024; ++it) {
    const int e0 = base + (it * 256 + tid) * 4;
    if (e0 >= N_EDGES) continue;
    const int4 d4 = *(const int4*)&dst[e0];
    const int4 s4 = *(const int4*)&src[e0];
    const float4 w4 = *(const float4*)&ew[e0];
#pragma unroll
    for (int j = 0; j < 4; ++j) {
      const int d = (j == 0) ? d4.x : (j == 1) ? d4.y : (j == 2) ? d4.z : d4.w;
      const int s = (j == 0) ? s4.x : (j == 1) ? s4.y : (j == 2) ? s4.z : s4.w;
      const float w = (j == 0) ? w4.x : (j == 1) ? w4.y : (j == 2) ? w4.z
                                                                   : w4.w;
      uint wfix = (uint)(w * 32768.0f + 0.5f);
      wfix = (wfix > 32767u) ? 32767u : wfix;
      const int pos = atomicAdd(&offs[d / BUCK_NODES], 1);
      uint2 p;
      p.x = (uint)d;
      p.y = (uint)s | (wfix << 17);
      stage[pos] = p;
    }
  }
  __syncthreads();

  int total = N_EDGES - base;
  if (total > CHUNK) total = CHUNK;
  for (int i = tid; i < total; i += 256) {
    const uint2 e = stage[i];
    const int b = (int)e.x / BUCK_NODES;
    ebuf[gbase[b] + (i - bstart[b])] = e;
  }
}

__global__ __launch_bounds__(512) void bucket_build(
    const int* __restrict__ bbase, const uint2* __restrict__ ebuf,
    uint* __restrict__ ecsr, int* __restrict__ row_ptr) {
  __shared__ uint outb[BCAP];  // 32 KB
  __shared__ int sh[512];
  __shared__ int cur[BUCK_NODES];
  const int b = blockIdx.x;
  const int n0 = b * BUCK_NODES;
  if (n0 >= N_NODES) return;
  int n1 = n0 + BUCK_NODES;
  if (n1 > N_NODES) n1 = N_NODES;
  const int nn = n1 - n0;
  const int beg = bbase[b];
  const int end = bbase[b + 1];
  const int t = threadIdx.x;

  if (t < BUCK_NODES) cur[t] = 0;
  __syncthreads();
  for (int i = beg + t; i < end; i += 512)
    atomicAdd(&cur[(int)ebuf[i].x - n0], 1);
  __syncthreads();
  const int v = (t < nn) ? cur[t] : 0;
  sh[t] = v;
  __syncthreads();
  for (int off = 1; off < 512; off <<= 1) {
    const int a = (t >= off) ? sh[t - off] : 0;
    __syncthreads();
    sh[t] += a;
    __syncthreads();
  }
  const int ex = sh[t] - v;
  if (t < nn) {
    row_ptr[n0 + t] = beg + ex;
    cur[t] = ex;
  }
  __syncthreads();
  for (int i = beg + t; i < end; i += 512) {
    const uint2 e = ebuf[i];
    const int local = atomicAdd(&cur[(int)e.x - n0], 1);
    outb[local] = e.y;
  }
  __syncthreads();
  const int cnt = end - beg;
  for (int i = t; i < cnt; i += 512) ecsr[beg + i] = outb[i];
}

// ---------------------------------------------------------------------------
// aggregate: out[n][:] = relu( sum_{e} H8[col[e]][:]*wv[e] + bias )
// one QUARTER-wave (16 lanes) per node, 8 fp8 cols per lane (8B loads ->
// row = one 128B line), 8-edge unroll, fp32 accumulate. 4B descriptors.
// ---------------------------------------------------------------------------
template <int OUTF32>
__global__ __launch_bounds__(256) void aggregate_b(
    const uchar* __restrict__ H8, const int* __restrict__ row_ptr,
    const uint* __restrict__ ecsr, const float* __restrict__ bias,
    float* __restrict__ outf, ushort* __restrict__ outb) {
  const int node = blockIdx.x * 16 + (threadIdx.x >> 4);
  const int lane = threadIdx.x & 15;  // 16 lanes, 8 fp8 cols each
  if (node >= N_NODES) return;
  int i = row_ptr[node];
  const int end = row_ptr[node + 1];
  float a0 = 0.f, a1 = 0.f, a2 = 0.f, a3 = 0.f;
  float a4 = 0.f, a5 = 0.f, a6 = 0.f, a7 = 0.f;
  const float wscale = 1.0f / 32768.0f;
  for (; i + 8 <= end; i += 8) {
    uint e[8];
    uint2 hv[8];
#pragma unroll
    for (int j = 0; j < 8; ++j) e[j] = ecsr[i + j];
#pragma unroll
    for (int j = 0; j < 8; ++j)
      hv[j] = *(const uint2*)&H8[(size_t)(e[j] & 0x1FFFFu) * DIM + lane * 8];
#pragma unroll
    for (int j = 0; j < 8; ++j) {
      const float w = (float)(e[j] >> 17) * wscale;
      const f32x2 c01 = __builtin_amdgcn_cvt_pk_f32_fp8((int)hv[j].x, false);
      const f32x2 c23 = __builtin_amdgcn_cvt_pk_f32_fp8((int)hv[j].x, true);
      const f32x2 c45 = __builtin_amdgcn_cvt_pk_f32_fp8((int)hv[j].y, false);
      const f32x2 c67 = __builtin_amdgcn_cvt_pk_f32_fp8((int)hv[j].y, true);
      a0 += w * c01.x;
      a1 += w * c01.y;
      a2 += w * c23.x;
      a3 += w * c23.y;
      a4 += w * c45.x;
      a5 += w * c45.y;
      a6 += w * c67.x;
      a7 += w * c67.y;
    }
  }
  for (; i < end; ++i) {
    const uint e0 = ecsr[i];
    const float w = (float)(e0 >> 17) * wscale;
    const uint2 hv = *(const uint2*)&H8[(size_t)(e0 & 0x1FFFFu) * DIM + lane * 8];
    const f32x2 c01 = __builtin_amdgcn_cvt_pk_f32_fp8((int)hv.x, false);
    const f32x2 c23 = __builtin_amdgcn_cvt_pk_f32_fp8((int)hv.x, true);
    const f32x2 c45 = __builtin_amdgcn_cvt_pk_f32_fp8((int)hv.y, false);
    const f32x2 c67 = __builtin_amdgcn_cvt_pk_f32_fp8((int)hv.y, true);
    a0 += w * c01.x;
    a1 += w * c01.y;
    a2 += w * c23.x;
    a3 += w * c23.y;
    a4 += w * c45.x;
    a5 += w * c45.y;
    a6 += w * c67.x;
    a7 += w * c67.y;
  }
  const float4 b0 = *(const float4*)&bias[lane * 8];
  const float4 b1 = *(const float4*)&bias[lane * 8 + 4];
  a0 = fmaxf(a0 + b0.x, 0.f);
  a1 = fmaxf(a1 + b0.y, 0.f);
  a2 = fmaxf(a2 + b0.z, 0.f);
  a3 = fmaxf(a3 + b0.w, 0.f);
  a4 = fmaxf(a4 + b1.x, 0.f);
  a5 = fmaxf(a5 + b1.y, 0.f);
  a6 = fmaxf(a6 + b1.z, 0.f);
  a7 = fmaxf(a7 + b1.w, 0.f);
  if (OUTF32) {
    float4 o0 = {a0, a1, a2, a3};
    float4 o1 = {a4, a5, a6, a7};
    *(float4*)&outf[(size_t)node * DIM + lane * 8] = o0;
    *(float4*)&outf[(size_t)node * DIM + lane * 8 + 4] = o1;
  } else {
    u32x4 p;
    p.x = (uint)f2bf(a0) | ((uint)f2bf(a1) << 16);
    p.y = (uint)f2bf(a2) | ((uint)f2bf(a3) << 16);
    p.z = (uint)f2bf(a4) | ((uint)f2bf(a5) << 16);
    p.w = (uint)f2bf(a6) | ((uint)f2bf(a7) << 16);
    *(u32x4*)&outb[(size_t)node * DIM + lane * 8] = p;
  }
}

extern "C" void kernel_launch(void* const* d_in, const int* in_sizes, int n_in,
                              void* d_out, int out_size, void* d_ws,
                              size_t ws_size, hipStream_t stream) {
  const float* x = (const float*)d_in[0];
  const int* esrc = (const int*)d_in[1];
  const int* edst = (const int*)d_in[2];
  const float* ew = (const float*)d_in[3];
  const float* W = (const float*)d_in[4];
  const float* b = (const float*)d_in[5];
  float* out = (float*)d_out;

  // workspace layout
  uchar* h8_buf = (uchar*)d_ws;                         // [N*D] fp8 (12.8MB)
  ushort* act_buf = (ushort*)(h8_buf + (size_t)N_NODES * DIM);  // [N*D] bf16
  ushort* Wt = act_buf + (size_t)N_NODES * DIM;         // [3*128*128] bf16
  uint* ecsr = (uint*)(Wt + 3 * DIM * DIM);             // [E] packed src|w
  uint2* ebuf = (uint2*)(ecsr + N_EDGES);               // [E] (dst, src|w)
  int* cnt2d = (int*)(ebuf + N_EDGES);                  // [ABLOCKS*NBUCK]
  int* bbase = cnt2d + ABLOCKS * NBUCK;                 // [NBUCK+1]
  int* row_ptr = bbase + NBUCK + 1;                     // [N+1]

  prep_wt<<<3 * DIM * DIM / 256, 256, 0, stream>>>(W, Wt);

  // ---- CSR build (once, reused by all 3 layers) ----
  bin_hist<<<ABLOCKS, 256, 0, stream>>>(edst, cnt2d);
  bin_scan<<<1, 256, 0, stream>>>(cnt2d, bbase, row_ptr);
  bin_scatter<<<ABLOCKS, 256, 0, stream>>>(esrc, edst, ew, cnt2d, ebuf);
  bucket_build<<<NBUCK, 512, 0, stream>>>(bbase, ebuf, ecsr, row_ptr);

  const int gemm_blocks = (N_NODES + 63) / 64;  // 1563
  const int agg_blocks = (N_NODES + 15) / 16;   // 6250

  // layer 0: fp32 x -> h8 ; aggregate -> act (bf16)
  gemm_f32in<<<gemm_blocks, 256, 0, stream>>>(x, Wt, h8_buf);
  aggregate_b<0><<<agg_blocks, 256, 0, stream>>>(h8_buf, row_ptr, ecsr, b,
                                                 nullptr, act_buf);
  // layer 1: act -> h8 ; aggregate -> act
  gemm_bf16in<<<gemm_blocks, 256, 0, stream>>>(act_buf, Wt + DIM * DIM, h8_buf);
  aggregate_b<0><<<agg_blocks, 256, 0, stream>>>(h8_buf, row_ptr, ecsr, b + DIM,
                                                 nullptr, act_buf);
  // layer 2: act -> h8 ; aggregate -> out (fp32)
  gemm_bf16in<<<gemm_blocks, 256, 0, stream>>>(act_buf, Wt + 2 * DIM * DIM,
                                               h8_buf);
  aggregate_b<1><<<agg_blocks, 256, 0, stream>>>(h8_buf, row_ptr, ecsr,
                                                 b + 2 * DIM, out, nullptr);
}